// Round 1
// baseline (481.309 us; speedup 1.0000x reference)
//
#include <hip/hip_runtime.h>
#include <math.h>

#define NFEAT 128
#define NHID  128
#define ALPHA 0.2f

// Kernel A: h = x @ W  (written straight into d_out), plus per-row
// s1[i] = h[i,:]·a1, s2[i] = h[i,:]·a2.
// 8 rows per block; thread t -> rowslot = t>>5, j-group jg = t&31 (4 cols as float4).
__global__ __launch_bounds__(256) void gemm_h_kernel(
    const float* __restrict__ x, const float* __restrict__ W,
    const float* __restrict__ a, float* __restrict__ h,
    float* __restrict__ s1, float* __restrict__ s2)
{
    __shared__ float xs[8][NFEAT];
    const int t      = threadIdx.x;
    const int block0 = blockIdx.x * 8;

    // Stage 8 x-rows (1024 floats) into LDS with 256 float4 loads.
    {
        const float4* x4  = (const float4*)(x + (size_t)block0 * NFEAT);
        float4*       xs4 = (float4*)&xs[0][0];
        xs4[t] = x4[t];
    }
    __syncthreads();

    const int rowslot = t >> 5;
    const int jg      = t & 31;
    const float4* W4  = (const float4*)W;
    const float4  a1v = ((const float4*)a)[jg];
    const float4  a2v = ((const float4*)a)[32 + jg];

    float4 acc = make_float4(0.f, 0.f, 0.f, 0.f);
    #pragma unroll 8
    for (int k = 0; k < NFEAT; ++k) {
        const float  xv = xs[rowslot][k];
        const float4 w  = W4[k * 32 + jg];
        acc.x = fmaf(xv, w.x, acc.x);
        acc.y = fmaf(xv, w.y, acc.y);
        acc.z = fmaf(xv, w.z, acc.z);
        acc.w = fmaf(xv, w.w, acc.w);
    }

    const int row = block0 + rowslot;
    ((float4*)(h + (size_t)row * NHID))[jg] = acc;

    // Row dot with a1/a2, reduced across the 32-lane j-group.
    float p1 = acc.x * a1v.x + acc.y * a1v.y + acc.z * a1v.z + acc.w * a1v.w;
    float p2 = acc.x * a2v.x + acc.y * a2v.y + acc.z * a2v.z + acc.w * a2v.w;
    #pragma unroll
    for (int off = 16; off >= 1; off >>= 1) {
        p1 += __shfl_xor(p1, off, 64);
        p2 += __shfl_xor(p2, off, 64);
    }
    if (jg == 0) { s1[row] = p1; s2[row] = p2; }
}

// Kernel B: one 64-lane wave per edge.
// score = s1[src] + s2[dst]; ev = exp(-leaky_relu(score, 0.2));
// hprime[src,:] += ev * h[dst,:]; rowsum[src] += ev.
__global__ __launch_bounds__(256) void edge_kernel(
    const int* __restrict__ ei, const float* __restrict__ h,
    const float* __restrict__ s1, const float* __restrict__ s2,
    float* __restrict__ hprime, float* __restrict__ rowsum, int E)
{
    const int wave = (int)((blockIdx.x * 256u + threadIdx.x) >> 6);
    const int lane = threadIdx.x & 63;
    if (wave >= E) return;

    const int src = ei[wave];
    const int dst = ei[E + wave];

    const float s   = s1[src] + s2[dst];
    const float lre = (s > 0.f) ? s : ALPHA * s;
    const float ev  = expf(-lre);

    const float* hd = h      + (size_t)dst * NHID;
    float*       hp = hprime + (size_t)src * NHID;

    atomicAdd(&hp[lane],      ev * hd[lane]);
    atomicAdd(&hp[lane + 64], ev * hd[lane + 64]);
    if (lane == 0) atomicAdd(&rowsum[src], ev);
}

// Kernel C: out = elu(h - hprime / (rowsum + 1e-16)), in place over h (=d_out).
__global__ __launch_bounds__(256) void finalize_kernel(
    float* __restrict__ h_out, const float* __restrict__ hprime,
    const float* __restrict__ rowsum, int total4)
{
    const int idx = blockIdx.x * 256 + threadIdx.x;  // float4 index
    if (idx >= total4) return;
    const int node = idx >> 5;  // 32 float4 per row

    const float  rinv = 1.0f / (rowsum[node] + 1e-16f);
    const float4 hv = ((const float4*)h_out)[idx];
    const float4 hp = ((const float4*)hprime)[idx];

    float4 o;
    float z;
    z = hv.x - hp.x * rinv; o.x = (z > 0.f) ? z : (expf(z) - 1.f);
    z = hv.y - hp.y * rinv; o.y = (z > 0.f) ? z : (expf(z) - 1.f);
    z = hv.z - hp.z * rinv; o.z = (z > 0.f) ? z : (expf(z) - 1.f);
    z = hv.w - hp.w * rinv; o.w = (z > 0.f) ? z : (expf(z) - 1.f);

    ((float4*)h_out)[idx] = o;
}

extern "C" void kernel_launch(void* const* d_in, const int* in_sizes, int n_in,
                              void* d_out, int out_size, void* d_ws, size_t ws_size,
                              hipStream_t stream) {
    const float* x  = (const float*)d_in[0];
    const float* W  = (const float*)d_in[1];
    const float* a  = (const float*)d_in[2];
    const int*   ei = (const int*)d_in[3];

    const int n = in_sizes[0] / NFEAT;   // 50000
    const int E = in_sizes[3] / 2;       // 640000

    float* h = (float*)d_out;            // h lives in d_out; finalize is in-place

    // Workspace layout: hprime[n*128] | rowsum[n] | s1[n] | s2[n]
    float* ws     = (float*)d_ws;
    float* hprime = ws;
    float* rowsum = ws + (size_t)n * NHID;
    float* s1     = rowsum + n;
    float* s2     = s1 + n;

    // Zero the atomic accumulators (hprime + rowsum are contiguous).
    hipMemsetAsync(hprime, 0, ((size_t)n * NHID + (size_t)n) * sizeof(float), stream);

    gemm_h_kernel<<<n / 8, 256, 0, stream>>>(x, W, a, h, s1, s2);

    edge_kernel<<<(E + 3) / 4, 256, 0, stream>>>(ei, h, s1, s2, hprime, rowsum, E);

    const int total4 = n * (NHID / 4);
    finalize_kernel<<<(total4 + 255) / 256, 256, 0, stream>>>(h, hprime, rowsum, total4);
}

// Round 2
// 243.642 us; speedup vs baseline: 1.9755x; 1.9755x over previous
//
#include <hip/hip_runtime.h>
#include <math.h>

#define NFEAT 128
#define NHID  128
#define ALPHA 0.2f

// ---------------------------------------------------------------------------
// Kernel A: h = x @ W (into ws), plus s1 = h·a1, s2 = h·a2 per row.
// 32 rows/block. W (64 KB) and x^T (16 KB) staged in LDS.
// Thread t: jg = t&31 (float4 col group), rg = t>>5 (4 rows rg*4..rg*4+3).
// ---------------------------------------------------------------------------
__global__ __launch_bounds__(256) void gemm_h_kernel(
    const float* __restrict__ x, const float* __restrict__ W,
    const float* __restrict__ a, float* __restrict__ h,
    float* __restrict__ s1, float* __restrict__ s2, int n)
{
    __shared__ float Ws[NFEAT * NHID];   // 64 KB, [k][j] row-major
    __shared__ float xs[NFEAT * 32];     // 16 KB, [k][r] (transposed)

    const int t    = threadIdx.x;
    const int row0 = blockIdx.x * 32;

    // Stage W: 16384 floats = 4096 float4, 16 per thread.
    {
        const float4* W4  = (const float4*)W;
        float4*       Ws4 = (float4*)Ws;
        #pragma unroll
        for (int i = 0; i < 16; ++i) Ws4[t + 256 * i] = W4[t + 256 * i];
    }
    // Stage x rows row0..row0+31 transposed. r = t&31, kb = t>>5 covers k=kb*16..+15.
    {
        const int r  = t & 31;
        const int kb = t >> 5;
        int rr = row0 + r; if (rr >= n) rr = n - 1;   // clamp (reads only)
        const float4* xr = (const float4*)(x + (size_t)rr * NFEAT);
        #pragma unroll
        for (int i = 0; i < 4; ++i) {
            const float4 v = xr[kb * 4 + i];
            const int k = kb * 16 + i * 4;
            xs[(k + 0) * 32 + r] = v.x;
            xs[(k + 1) * 32 + r] = v.y;
            xs[(k + 2) * 32 + r] = v.z;
            xs[(k + 3) * 32 + r] = v.w;
        }
    }
    __syncthreads();

    const int jg = t & 31;
    const int rg = t >> 5;
    const float4* Ws4 = (const float4*)Ws;
    const float4* xs4 = (const float4*)xs;

    float4 acc[4];
    #pragma unroll
    for (int r = 0; r < 4; ++r) acc[r] = make_float4(0.f, 0.f, 0.f, 0.f);

    #pragma unroll 4
    for (int k = 0; k < NFEAT; ++k) {
        const float4 w  = Ws4[k * 32 + jg];   // broadcast within half-wave pairs
        const float4 xv = xs4[k * 8 + rg];    // 32-way broadcast per half-wave
        acc[0].x = fmaf(xv.x, w.x, acc[0].x); acc[0].y = fmaf(xv.x, w.y, acc[0].y);
        acc[0].z = fmaf(xv.x, w.z, acc[0].z); acc[0].w = fmaf(xv.x, w.w, acc[0].w);
        acc[1].x = fmaf(xv.y, w.x, acc[1].x); acc[1].y = fmaf(xv.y, w.y, acc[1].y);
        acc[1].z = fmaf(xv.y, w.z, acc[1].z); acc[1].w = fmaf(xv.y, w.w, acc[1].w);
        acc[2].x = fmaf(xv.z, w.x, acc[2].x); acc[2].y = fmaf(xv.z, w.y, acc[2].y);
        acc[2].z = fmaf(xv.z, w.z, acc[2].z); acc[2].w = fmaf(xv.z, w.w, acc[2].w);
        acc[3].x = fmaf(xv.w, w.x, acc[3].x); acc[3].y = fmaf(xv.w, w.y, acc[3].y);
        acc[3].z = fmaf(xv.w, w.z, acc[3].z); acc[3].w = fmaf(xv.w, w.w, acc[3].w);
    }

    const float4 a1 = ((const float4*)a)[jg];
    const float4 a2 = ((const float4*)a)[32 + jg];

    #pragma unroll
    for (int r = 0; r < 4; ++r) {
        const int row = row0 + rg * 4 + r;
        if (row < n) ((float4*)(h + (size_t)row * NHID))[jg] = acc[r];

        float p1 = acc[r].x * a1.x + acc[r].y * a1.y + acc[r].z * a1.z + acc[r].w * a1.w;
        float p2 = acc[r].x * a2.x + acc[r].y * a2.y + acc[r].z * a2.z + acc[r].w * a2.w;
        #pragma unroll
        for (int off = 16; off >= 1; off >>= 1) {
            p1 += __shfl_xor(p1, off, 64);   // stays within the 32-lane jg group
            p2 += __shfl_xor(p2, off, 64);
        }
        if (jg == 0 && row < n) { s1[row] = p1; s2[row] = p2; }
    }
}

// ---------------------------------------------------------------------------
// CSR build: histogram -> 2-level exclusive scan -> scatter (with ev compute)
// ---------------------------------------------------------------------------
__global__ __launch_bounds__(256) void hist_kernel(
    const int* __restrict__ ei, int* __restrict__ hist, int E)
{
    const int j = blockIdx.x * 256 + threadIdx.x;
    if (j < E) atomicAdd(&hist[ei[j]], 1);
}

// Per-256 block exclusive scan (Hillis-Steele), block totals to bsums.
__global__ __launch_bounds__(256) void scan_block_kernel(
    const int* __restrict__ in, int* __restrict__ out, int* __restrict__ bsums, int n)
{
    __shared__ int s[256];
    const int tid = threadIdx.x;
    const int gid = blockIdx.x * 256 + tid;
    const int v = (gid < n) ? in[gid] : 0;
    s[tid] = v;
    __syncthreads();
    #pragma unroll
    for (int off = 1; off < 256; off <<= 1) {
        const int t2 = (tid >= off) ? s[tid - off] : 0;
        __syncthreads();
        s[tid] += t2;
        __syncthreads();
    }
    if (gid < n) out[gid] = s[tid] - v;           // exclusive
    if (tid == 255 && bsums) bsums[blockIdx.x] = s[255];
}

__global__ __launch_bounds__(256) void scan_add_kernel(
    int* __restrict__ row_ptr, int* __restrict__ cursor,
    const int* __restrict__ bsums_scan, int n, int E)
{
    const int gid = blockIdx.x * 256 + threadIdx.x;
    if (gid < n) {
        const int v = row_ptr[gid] + bsums_scan[gid >> 8];
        row_ptr[gid] = v;
        cursor[gid]  = v;
    }
    if (gid == 0) row_ptr[n] = E;
}

__global__ __launch_bounds__(256) void scatter_kernel(
    const int* __restrict__ ei, const float* __restrict__ s1,
    const float* __restrict__ s2, int* __restrict__ cursor,
    int* __restrict__ sorted_dst, float* __restrict__ sorted_ev, int E)
{
    const int j = blockIdx.x * 256 + threadIdx.x;
    if (j >= E) return;
    const int src = ei[j];
    const int dst = ei[E + j];
    const float s   = s1[src] + s2[dst];
    const float lre = (s > 0.f) ? s : ALPHA * s;
    const float ev  = expf(-lre);
    const int pos = atomicAdd(&cursor[src], 1);
    sorted_dst[pos] = dst;
    sorted_ev[pos]  = ev;
}

// ---------------------------------------------------------------------------
// Aggregate + finalize (fused): one wave per node.
// acc = sum_e ev*h[dst]; out[i] = elu(h[i] - acc/(rowsum+1e-16)).
// ---------------------------------------------------------------------------
__global__ __launch_bounds__(256) void aggregate_kernel(
    const int* __restrict__ row_ptr, const int* __restrict__ sorted_dst,
    const float* __restrict__ sorted_ev, const float* __restrict__ h,
    float* __restrict__ out, int n)
{
    const int node = blockIdx.x * 4 + (threadIdx.x >> 6);
    const int lane = threadIdx.x & 63;
    if (node >= n) return;

    const int beg = row_ptr[node];
    const int end = row_ptr[node + 1];

    float acc0 = 0.f, acc1 = 0.f, rs = 0.f;

    int e = beg;
    int   dstn = 0;
    float evn  = 0.f;
    if (e < end) { dstn = sorted_dst[e]; evn = sorted_ev[e]; }
    while (e < end) {
        const int   dst = dstn;
        const float ev  = evn;
        ++e;
        if (e < end) { dstn = sorted_dst[e]; evn = sorted_ev[e]; }  // prefetch
        const float* hd = h + (size_t)dst * NHID;
        acc0 = fmaf(ev, hd[lane],      acc0);
        acc1 = fmaf(ev, hd[lane + 64], acc1);
        rs  += ev;
    }

    const float rinv = 1.0f / (rs + 1e-16f);
    const float hv0 = h[(size_t)node * NHID + lane];
    const float hv1 = h[(size_t)node * NHID + 64 + lane];
    const float z0 = hv0 - acc0 * rinv;
    const float z1 = hv1 - acc1 * rinv;
    out[(size_t)node * NHID + lane]      = (z0 > 0.f) ? z0 : (expf(z0) - 1.f);
    out[(size_t)node * NHID + 64 + lane] = (z1 > 0.f) ? z1 : (expf(z1) - 1.f);
}

// ---------------------------------------------------------------------------
extern "C" void kernel_launch(void* const* d_in, const int* in_sizes, int n_in,
                              void* d_out, int out_size, void* d_ws, size_t ws_size,
                              hipStream_t stream) {
    const float* x  = (const float*)d_in[0];
    const float* W  = (const float*)d_in[1];
    const float* a  = (const float*)d_in[2];
    const int*   ei = (const int*)d_in[3];

    const int n = in_sizes[0] / NFEAT;   // 50000
    const int E = in_sizes[3] / 2;       // 640000
    const int nb = (n + 255) / 256;      // 196 scan blocks

    float* out = (float*)d_out;

    // Workspace layout (4-byte elements):
    //   h[n*128] | s1[n] | s2[n] | sorted_ev[E] | sorted_dst[E] |
    //   hist[n] | row_ptr[n+1] | cursor[n] | bsums[256] | bsums_scan[256]
    float* ws         = (float*)d_ws;
    float* h          = ws;
    float* s1         = h + (size_t)n * NHID;
    float* s2         = s1 + n;
    float* sorted_ev  = s2 + n;
    int*   sorted_dst = (int*)(sorted_ev + E);
    int*   hist       = sorted_dst + E;
    int*   row_ptr    = hist + n;
    int*   cursor     = row_ptr + (n + 1);
    int*   bsums      = cursor + n;
    int*   bsums_scan = bsums + 256;

    // Zero histogram (+ level-2 scan padding).
    hipMemsetAsync(hist, 0, (size_t)n * sizeof(int), stream);
    hipMemsetAsync(bsums, 0, 256 * sizeof(int), stream);

    gemm_h_kernel<<<(n + 31) / 32, 256, 0, stream>>>(x, W, a, h, s1, s2, n);

    hist_kernel<<<(E + 255) / 256, 256, 0, stream>>>(ei, hist, E);

    scan_block_kernel<<<nb, 256, 0, stream>>>(hist, row_ptr, bsums, n);
    scan_block_kernel<<<1, 256, 0, stream>>>(bsums, bsums_scan, nullptr, 256);
    scan_add_kernel<<<nb, 256, 0, stream>>>(row_ptr, cursor, bsums_scan, n, E);

    scatter_kernel<<<(E + 255) / 256, 256, 0, stream>>>(ei, s1, s2, cursor,
                                                        sorted_dst, sorted_ev, E);

    aggregate_kernel<<<(n + 3) / 4, 256, 0, stream>>>(row_ptr, sorted_dst,
                                                      sorted_ev, h, out, n);
}

// Round 3
// 229.750 us; speedup vs baseline: 2.0949x; 1.0605x over previous
//
#include <hip/hip_runtime.h>
#include <math.h>

#define NFEAT 128
#define NHID  128
#define ALPHA 0.2f

__device__ inline unsigned int pack_bf16x2_rn(float x, float y) {
    unsigned int bx = __float_as_uint(x), by = __float_as_uint(y);
    bx += 0x7fffu + ((bx >> 16) & 1u);
    by += 0x7fffu + ((by >> 16) & 1u);
    return (bx >> 16) | (by & 0xffff0000u);
}

// ---------------------------------------------------------------------------
// Kernel A: h = x @ W (fp32 into ws) + hb (bf16 copy for gathers),
// plus s1 = h·a1, s2 = h·a2 per row.
// 32 rows/block. W (64 KB) and x^T (16 KB) staged in LDS.
// ---------------------------------------------------------------------------
__global__ __launch_bounds__(256) void gemm_h_kernel(
    const float* __restrict__ x, const float* __restrict__ W,
    const float* __restrict__ a, float* __restrict__ h,
    unsigned short* __restrict__ hb,
    float* __restrict__ s1, float* __restrict__ s2, int n)
{
    __shared__ float Ws[NFEAT * NHID];   // 64 KB, [k][j]
    __shared__ float xs[NFEAT * 32];     // 16 KB, [k][r]

    const int t    = threadIdx.x;
    const int row0 = blockIdx.x * 32;

    {
        const float4* W4  = (const float4*)W;
        float4*       Ws4 = (float4*)Ws;
        #pragma unroll
        for (int i = 0; i < 16; ++i) Ws4[t + 256 * i] = W4[t + 256 * i];
    }
    {
        const int r  = t & 31;
        const int kb = t >> 5;
        int rr = row0 + r; if (rr >= n) rr = n - 1;
        const float4* xr = (const float4*)(x + (size_t)rr * NFEAT);
        #pragma unroll
        for (int i = 0; i < 4; ++i) {
            const float4 v = xr[kb * 4 + i];
            const int k = kb * 16 + i * 4;
            xs[(k + 0) * 32 + r] = v.x;
            xs[(k + 1) * 32 + r] = v.y;
            xs[(k + 2) * 32 + r] = v.z;
            xs[(k + 3) * 32 + r] = v.w;
        }
    }
    __syncthreads();

    const int jg = t & 31;
    const int rg = t >> 5;
    const float4* Ws4 = (const float4*)Ws;
    const float4* xs4 = (const float4*)xs;

    float4 acc[4];
    #pragma unroll
    for (int r = 0; r < 4; ++r) acc[r] = make_float4(0.f, 0.f, 0.f, 0.f);

    #pragma unroll 4
    for (int k = 0; k < NFEAT; ++k) {
        const float4 w  = Ws4[k * 32 + jg];
        const float4 xv = xs4[k * 8 + rg];
        acc[0].x = fmaf(xv.x, w.x, acc[0].x); acc[0].y = fmaf(xv.x, w.y, acc[0].y);
        acc[0].z = fmaf(xv.x, w.z, acc[0].z); acc[0].w = fmaf(xv.x, w.w, acc[0].w);
        acc[1].x = fmaf(xv.y, w.x, acc[1].x); acc[1].y = fmaf(xv.y, w.y, acc[1].y);
        acc[1].z = fmaf(xv.y, w.z, acc[1].z); acc[1].w = fmaf(xv.y, w.w, acc[1].w);
        acc[2].x = fmaf(xv.z, w.x, acc[2].x); acc[2].y = fmaf(xv.z, w.y, acc[2].y);
        acc[2].z = fmaf(xv.z, w.z, acc[2].z); acc[2].w = fmaf(xv.z, w.w, acc[2].w);
        acc[3].x = fmaf(xv.w, w.x, acc[3].x); acc[3].y = fmaf(xv.w, w.y, acc[3].y);
        acc[3].z = fmaf(xv.w, w.z, acc[3].z); acc[3].w = fmaf(xv.w, w.w, acc[3].w);
    }

    const float4 a1 = ((const float4*)a)[jg];
    const float4 a2 = ((const float4*)a)[32 + jg];

    #pragma unroll
    for (int r = 0; r < 4; ++r) {
        const int row = row0 + rg * 4 + r;
        if (row < n) {
            ((float4*)(h + (size_t)row * NHID))[jg] = acc[r];
            uint2 pk;
            pk.x = pack_bf16x2_rn(acc[r].x, acc[r].y);
            pk.y = pack_bf16x2_rn(acc[r].z, acc[r].w);
            ((uint2*)(hb + (size_t)row * NHID))[jg] = pk;
        }

        float p1 = acc[r].x * a1.x + acc[r].y * a1.y + acc[r].z * a1.z + acc[r].w * a1.w;
        float p2 = acc[r].x * a2.x + acc[r].y * a2.y + acc[r].z * a2.z + acc[r].w * a2.w;
        #pragma unroll
        for (int off = 16; off >= 1; off >>= 1) {
            p1 += __shfl_xor(p1, off, 64);
            p2 += __shfl_xor(p2, off, 64);
        }
        if (jg == 0 && row < n) { s1[row] = p1; s2[row] = p2; }
    }
}

// ---------------------------------------------------------------------------
// CSR build: histogram -> 2-level exclusive scan -> scatter (with ev compute)
// ---------------------------------------------------------------------------
__global__ __launch_bounds__(256) void hist_kernel(
    const int* __restrict__ ei, int* __restrict__ hist, int E)
{
    const int j = blockIdx.x * 256 + threadIdx.x;
    if (j < E) atomicAdd(&hist[ei[j]], 1);
}

__global__ __launch_bounds__(256) void scan_block_kernel(
    const int* __restrict__ in, int* __restrict__ out, int* __restrict__ bsums, int n)
{
    __shared__ int s[256];
    const int tid = threadIdx.x;
    const int gid = blockIdx.x * 256 + tid;
    const int v = (gid < n) ? in[gid] : 0;
    s[tid] = v;
    __syncthreads();
    #pragma unroll
    for (int off = 1; off < 256; off <<= 1) {
        const int t2 = (tid >= off) ? s[tid - off] : 0;
        __syncthreads();
        s[tid] += t2;
        __syncthreads();
    }
    if (gid < n) out[gid] = s[tid] - v;
    if (tid == 255 && bsums) bsums[blockIdx.x] = s[255];
}

__global__ __launch_bounds__(256) void scan_add_kernel(
    int* __restrict__ row_ptr, int* __restrict__ cursor,
    const int* __restrict__ bsums_scan, int n, int E)
{
    const int gid = blockIdx.x * 256 + threadIdx.x;
    if (gid < n) {
        const int v = row_ptr[gid] + bsums_scan[gid >> 8];
        row_ptr[gid] = v;
        cursor[gid]  = v;
    }
    if (gid == 0) row_ptr[n] = E;
}

// Pack (dst, ev) into one 8-byte record: one random store instead of two.
__global__ __launch_bounds__(256) void scatter_kernel(
    const int* __restrict__ ei, const float* __restrict__ s1,
    const float* __restrict__ s2, int* __restrict__ cursor,
    int2* __restrict__ epack, int E)
{
    const int j = blockIdx.x * 256 + threadIdx.x;
    if (j >= E) return;
    const int src = ei[j];
    const int dst = ei[E + j];
    const float s   = s1[src] + s2[dst];
    const float lre = (s > 0.f) ? s : ALPHA * s;
    const float ev  = expf(-lre);
    const int pos = atomicAdd(&cursor[src], 1);
    epack[pos] = make_int2(dst, __float_as_int(ev));
}

// ---------------------------------------------------------------------------
// Aggregate + finalize (fused): one wave per node, bf16 gathers.
// Lane l accumulates features 2l and 2l+1 (one 4 B bf16x2 load per edge).
// ---------------------------------------------------------------------------
__global__ __launch_bounds__(256) void aggregate_kernel(
    const int* __restrict__ row_ptr, const int2* __restrict__ epack,
    const unsigned short* __restrict__ hb, const float* __restrict__ h,
    float* __restrict__ out, int n)
{
    const int node = blockIdx.x * 4 + (threadIdx.x >> 6);
    const int lane = threadIdx.x & 63;
    if (node >= n) return;

    const int beg = row_ptr[node];
    const int end = row_ptr[node + 1];

    float acc0 = 0.f, acc1 = 0.f, rs = 0.f;

    int e = beg;
    // 2-edge unrolled: two independent gathers in flight per iteration.
    for (; e + 2 <= end; e += 2) {
        const int2 p0 = epack[e];
        const int2 p1 = epack[e + 1];
        const float ev0 = __int_as_float(p0.y);
        const float ev1 = __int_as_float(p1.y);
        const unsigned int u0 =
            ((const unsigned int*)(hb + (size_t)p0.x * NHID))[lane];
        const unsigned int u1 =
            ((const unsigned int*)(hb + (size_t)p1.x * NHID))[lane];
        const float f0x = __uint_as_float(u0 << 16);
        const float f0y = __uint_as_float(u0 & 0xffff0000u);
        const float f1x = __uint_as_float(u1 << 16);
        const float f1y = __uint_as_float(u1 & 0xffff0000u);
        acc0 = fmaf(ev0, f0x, acc0); acc1 = fmaf(ev0, f0y, acc1);
        acc0 = fmaf(ev1, f1x, acc0); acc1 = fmaf(ev1, f1y, acc1);
        rs += ev0 + ev1;
    }
    if (e < end) {
        const int2 p0 = epack[e];
        const float ev0 = __int_as_float(p0.y);
        const unsigned int u0 =
            ((const unsigned int*)(hb + (size_t)p0.x * NHID))[lane];
        acc0 = fmaf(ev0, __uint_as_float(u0 << 16), acc0);
        acc1 = fmaf(ev0, __uint_as_float(u0 & 0xffff0000u), acc1);
        rs += ev0;
    }

    const float rinv = 1.0f / (rs + 1e-16f);
    const float2 hv = ((const float2*)(h + (size_t)node * NHID))[lane];
    const float z0 = hv.x - acc0 * rinv;
    const float z1 = hv.y - acc1 * rinv;
    float2 o;
    o.x = (z0 > 0.f) ? z0 : (expf(z0) - 1.f);
    o.y = (z1 > 0.f) ? z1 : (expf(z1) - 1.f);
    ((float2*)(out + (size_t)node * NHID))[lane] = o;
}

// ---------------------------------------------------------------------------
extern "C" void kernel_launch(void* const* d_in, const int* in_sizes, int n_in,
                              void* d_out, int out_size, void* d_ws, size_t ws_size,
                              hipStream_t stream) {
    const float* x  = (const float*)d_in[0];
    const float* W  = (const float*)d_in[1];
    const float* a  = (const float*)d_in[2];
    const int*   ei = (const int*)d_in[3];

    const int n = in_sizes[0] / NFEAT;   // 50000
    const int E = in_sizes[3] / 2;       // 640000
    const int nb = (n + 255) / 256;

    float* out = (float*)d_out;

    // Workspace layout (4-byte units):
    //   h[n*128] | hb[n*128 bf16 = n*64] | s1[n] | s2[n] | epack[E int2 = 2E] |
    //   hist[n] | row_ptr[n+1] | cursor[n] | bsums[256] | bsums_scan[256]
    float*          ws  = (float*)d_ws;
    float*          h   = ws;
    unsigned short* hb  = (unsigned short*)(h + (size_t)n * NHID);
    float*          s1  = (float*)(hb + (size_t)n * NHID);
    float*          s2  = s1 + n;
    int2*           epack = (int2*)(s2 + n);
    int*            hist  = (int*)(epack + E);
    int*            row_ptr = hist + n;
    int*            cursor  = row_ptr + (n + 1);
    int*            bsums   = cursor + n;
    int*            bsums_scan = bsums + 256;

    hipMemsetAsync(hist, 0, (size_t)n * sizeof(int), stream);
    hipMemsetAsync(bsums, 0, 256 * sizeof(int), stream);

    gemm_h_kernel<<<(n + 31) / 32, 256, 0, stream>>>(x, W, a, h, hb, s1, s2, n);

    hist_kernel<<<(E + 255) / 256, 256, 0, stream>>>(ei, hist, E);

    scan_block_kernel<<<nb, 256, 0, stream>>>(hist, row_ptr, bsums, n);
    scan_block_kernel<<<1, 256, 0, stream>>>(bsums, bsums_scan, nullptr, 256);
    scan_add_kernel<<<nb, 256, 0, stream>>>(row_ptr, cursor, bsums_scan, n, E);

    scatter_kernel<<<(E + 255) / 256, 256, 0, stream>>>(ei, s1, s2, cursor, epack, E);

    aggregate_kernel<<<(n + 3) / 4, 256, 0, stream>>>(row_ptr, epack, hb, h, out, n);
}

// Round 4
// 204.742 us; speedup vs baseline: 2.3508x; 1.1221x over previous
//
#include <hip/hip_runtime.h>
#include <math.h>

#define NFEAT 128
#define NHID  128
#define ALPHA 0.2f

typedef __attribute__((ext_vector_type(8))) short short8;
typedef __attribute__((ext_vector_type(4))) float f32x4;

__device__ inline unsigned int pack_bf16x2_rn(float x, float y) {
    unsigned int bx = __float_as_uint(x), by = __float_as_uint(y);
    bx += 0x7fffu + ((bx >> 16) & 1u);
    by += 0x7fffu + ((by >> 16) & 1u);
    return (bx >> 16) | (by & 0xffff0000u);
}

union Frag { unsigned int u[4]; uint4 v; short8 s; };

// ---------------------------------------------------------------------------
// MFMA bf16 GEMM: h = x @ W (fp32 out) + hb (bf16 packed) + s1/s2 row dots.
// Block = 256 thr = 4 waves; wave computes 32 rows x 128 cols
// (2 row-tiles x 8 col-tiles of 16x16, K=128 in 4 steps of 32).
// W^T staged in LDS as bf16, stride 68 dwords (uniform bank spread, 16B align).
// A-frags packed in-register from global x (each x element read exactly once).
// ---------------------------------------------------------------------------
__global__ __launch_bounds__(256) void gemm_h_kernel(
    const float* __restrict__ x, const float* __restrict__ W,
    const float* __restrict__ a, float* __restrict__ h,
    unsigned int* __restrict__ hbu,
    float* __restrict__ s1, float* __restrict__ s2, int n)
{
    __shared__ unsigned int Wtu[128 * 68];   // Wt[n][k] bf16 pairs, 34816 B

    const int t = threadIdx.x;

    // ---- stage W^T (bf16) ----
    // thread handles (nn, ch): k-chunk ch*8..ch*8+7 of row nn. 8 iters.
    #pragma unroll
    for (int i = 0; i < 8; ++i) {
        const int idx = i * 256 + t;
        const int nn  = idx & 127;
        const int ch  = idx >> 7;          // 0..15
        unsigned int u[4];
        #pragma unroll
        for (int jj = 0; jj < 4; ++jj) {
            const int k  = ch * 8 + jj * 2;
            const float f0 = W[(size_t)k * NHID + nn];
            const float f1 = W[(size_t)(k + 1) * NHID + nn];
            u[jj] = pack_bf16x2_rn(f0, f1);
        }
        *((uint4*)&Wtu[nn * 68 + ch * 4]) = make_uint4(u[0], u[1], u[2], u[3]);
    }
    __syncthreads();

    const int w    = t >> 6;
    const int lane = t & 63;
    const int c    = lane & 15;            // m / n / col within 16-tile
    const int quad = lane >> 4;            // 0..3

    const int rowbase = blockIdx.x * 128 + w * 32;

    float a1v[8], a2v[8];
    #pragma unroll
    for (int tt = 0; tt < 8; ++tt) {
        a1v[tt] = a[tt * 16 + c];
        a2v[tt] = a[NHID + tt * 16 + c];
    }

    f32x4 acc[2][8];
    #pragma unroll
    for (int rt = 0; rt < 2; ++rt)
        #pragma unroll
        for (int tt = 0; tt < 8; ++tt)
            acc[rt][tt] = (f32x4){0.f, 0.f, 0.f, 0.f};

    #pragma unroll
    for (int s = 0; s < 4; ++s) {          // k-step: k0 = s*32
        Frag afr[2];
        #pragma unroll
        for (int rt = 0; rt < 2; ++rt) {
            int row = rowbase + rt * 16 + c;       // A: m = lane&15
            if (row >= n) row = n - 1;             // clamp (loads only)
            const float* xp = x + (size_t)row * NFEAT + s * 32 + quad * 8;
            const float4 xa = *((const float4*)xp);
            const float4 xb = *((const float4*)(xp + 4));
            afr[rt].u[0] = pack_bf16x2_rn(xa.x, xa.y);
            afr[rt].u[1] = pack_bf16x2_rn(xa.z, xa.w);
            afr[rt].u[2] = pack_bf16x2_rn(xb.x, xb.y);
            afr[rt].u[3] = pack_bf16x2_rn(xb.z, xb.w);
        }
        #pragma unroll
        for (int tt = 0; tt < 8; ++tt) {
            Frag bfr;                       // B: n = lane&15, k = quad*8+j
            bfr.v = *((const uint4*)&Wtu[(tt * 16 + c) * 68 + s * 16 + quad * 4]);
            acc[0][tt] = __builtin_amdgcn_mfma_f32_16x16x32_bf16(
                afr[0].s, bfr.s, acc[0][tt], 0, 0, 0);
            acc[1][tt] = __builtin_amdgcn_mfma_f32_16x16x32_bf16(
                afr[1].s, bfr.s, acc[1][tt], 0, 0, 0);
        }
    }

    // ---- epilogue: h (fp32), hb (bf16x2), s1/s2.  D: col=lane&15, row=quad*4+r
    #pragma unroll
    for (int rt = 0; rt < 2; ++rt) {
        #pragma unroll
        for (int r = 0; r < 4; ++r) {
            const int  row = rowbase + rt * 16 + quad * 4 + r;
            const bool ok  = (row < n);
            float p1 = 0.f, p2 = 0.f;
            #pragma unroll
            for (int tt = 0; tt < 8; ++tt) {
                const float v = acc[rt][tt][r];
                if (ok) h[(size_t)row * NHID + tt * 16 + c] = v;
                const float nb = __shfl_xor(v, 1, 64);
                if (ok && ((c & 1) == 0))
                    hbu[(size_t)row * 64 + tt * 8 + (c >> 1)] = pack_bf16x2_rn(v, nb);
                p1 = fmaf(v, a1v[tt], p1);
                p2 = fmaf(v, a2v[tt], p2);
            }
            #pragma unroll
            for (int off = 1; off <= 8; off <<= 1) {
                p1 += __shfl_xor(p1, off, 64);
                p2 += __shfl_xor(p2, off, 64);
            }
            if (ok && c == 0) { s1[row] = p1; s2[row] = p2; }
        }
    }
}

// ---------------------------------------------------------------------------
// CSR build: histogram -> 2-level exclusive scan -> scatter (with ev compute)
// ---------------------------------------------------------------------------
__global__ __launch_bounds__(256) void hist_kernel(
    const int* __restrict__ ei, int* __restrict__ hist, int E)
{
    const int j = blockIdx.x * 256 + threadIdx.x;
    if (j < E) atomicAdd(&hist[ei[j]], 1);
}

__global__ __launch_bounds__(256) void scan_block_kernel(
    const int* __restrict__ in, int* __restrict__ out, int* __restrict__ bsums, int n)
{
    __shared__ int s[256];
    const int tid = threadIdx.x;
    const int gid = blockIdx.x * 256 + tid;
    const int v = (gid < n) ? in[gid] : 0;
    s[tid] = v;
    __syncthreads();
    #pragma unroll
    for (int off = 1; off < 256; off <<= 1) {
        const int t2 = (tid >= off) ? s[tid - off] : 0;
        __syncthreads();
        s[tid] += t2;
        __syncthreads();
    }
    if (gid < n) out[gid] = s[tid] - v;
    if (tid == 255 && bsums) bsums[blockIdx.x] = s[255];
}

__global__ __launch_bounds__(256) void scan_add_kernel(
    int* __restrict__ row_ptr, int* __restrict__ cursor,
    const int* __restrict__ bsums_scan, int n, int E)
{
    const int gid = blockIdx.x * 256 + threadIdx.x;
    if (gid < n) {
        const int v = row_ptr[gid] + bsums_scan[gid >> 8];
        row_ptr[gid] = v;
        cursor[gid]  = v;
    }
    if (gid == 0) row_ptr[n] = E;
}

__global__ __launch_bounds__(256) void scatter_kernel(
    const int* __restrict__ ei, const float* __restrict__ s1,
    const float* __restrict__ s2, int* __restrict__ cursor,
    int2* __restrict__ epack, int E)
{
    const int j = blockIdx.x * 256 + threadIdx.x;
    if (j >= E) return;
    const int src = ei[j];
    const int dst = ei[E + j];
    const float s   = s1[src] + s2[dst];
    const float lre = (s > 0.f) ? s : ALPHA * s;
    const float ev  = expf(-lre);
    const int pos = atomicAdd(&cursor[src], 1);
    epack[pos] = make_int2(dst, __float_as_int(ev));
}

// ---------------------------------------------------------------------------
// Aggregate + finalize: one wave per node, bf16 gathers, 4-deep unroll.
// ---------------------------------------------------------------------------
__global__ __launch_bounds__(256) void aggregate_kernel(
    const int* __restrict__ row_ptr, const int2* __restrict__ epack,
    const unsigned int* __restrict__ hbu, const float* __restrict__ h,
    float* __restrict__ out, int n)
{
    const int node = blockIdx.x * 4 + (threadIdx.x >> 6);
    const int lane = threadIdx.x & 63;
    if (node >= n) return;

    const int beg = row_ptr[node];
    const int end = row_ptr[node + 1];

    float acc0 = 0.f, acc1 = 0.f, rs = 0.f;

    int e = beg;
    for (; e + 4 <= end; e += 4) {
        const int2 p0 = epack[e],     p1 = epack[e + 1];
        const int2 p2 = epack[e + 2], p3 = epack[e + 3];
        const unsigned int u0 = hbu[(size_t)p0.x * 64 + lane];
        const unsigned int u1 = hbu[(size_t)p1.x * 64 + lane];
        const unsigned int u2 = hbu[(size_t)p2.x * 64 + lane];
        const unsigned int u3 = hbu[(size_t)p3.x * 64 + lane];
        const float ev0 = __int_as_float(p0.y), ev1 = __int_as_float(p1.y);
        const float ev2 = __int_as_float(p2.y), ev3 = __int_as_float(p3.y);
        acc0 = fmaf(ev0, __uint_as_float(u0 << 16), acc0);
        acc1 = fmaf(ev0, __uint_as_float(u0 & 0xffff0000u), acc1);
        acc0 = fmaf(ev1, __uint_as_float(u1 << 16), acc0);
        acc1 = fmaf(ev1, __uint_as_float(u1 & 0xffff0000u), acc1);
        acc0 = fmaf(ev2, __uint_as_float(u2 << 16), acc0);
        acc1 = fmaf(ev2, __uint_as_float(u2 & 0xffff0000u), acc1);
        acc0 = fmaf(ev3, __uint_as_float(u3 << 16), acc0);
        acc1 = fmaf(ev3, __uint_as_float(u3 & 0xffff0000u), acc1);
        rs += (ev0 + ev1) + (ev2 + ev3);
    }
    for (; e < end; ++e) {
        const int2 p0 = epack[e];
        const float ev0 = __int_as_float(p0.y);
        const unsigned int u0 = hbu[(size_t)p0.x * 64 + lane];
        acc0 = fmaf(ev0, __uint_as_float(u0 << 16), acc0);
        acc1 = fmaf(ev0, __uint_as_float(u0 & 0xffff0000u), acc1);
        rs += ev0;
    }

    const float rinv = 1.0f / (rs + 1e-16f);
    const float2 hv = ((const float2*)(h + (size_t)node * NHID))[lane];
    const float z0 = hv.x - acc0 * rinv;
    const float z1 = hv.y - acc1 * rinv;
    float2 o;
    o.x = (z0 > 0.f) ? z0 : (expf(z0) - 1.f);
    o.y = (z1 > 0.f) ? z1 : (expf(z1) - 1.f);
    ((float2*)(out + (size_t)node * NHID))[lane] = o;
}

// ---------------------------------------------------------------------------
extern "C" void kernel_launch(void* const* d_in, const int* in_sizes, int n_in,
                              void* d_out, int out_size, void* d_ws, size_t ws_size,
                              hipStream_t stream) {
    const float* x  = (const float*)d_in[0];
    const float* W  = (const float*)d_in[1];
    const float* a  = (const float*)d_in[2];
    const int*   ei = (const int*)d_in[3];

    const int n = in_sizes[0] / NFEAT;   // 50000
    const int E = in_sizes[3] / 2;       // 640000
    const int nb = (n + 255) / 256;

    float* out = (float*)d_out;

    // Workspace layout (4-byte units):
    //   h[n*128] | hbu[n*64] | s1[n] | s2[n] | epack[2E] |
    //   hist[n] | bsums[256] | bsums_scan[256] | row_ptr[n+1] | cursor[n]
    float*        h     = (float*)d_ws;
    unsigned int* hbu   = (unsigned int*)(h + (size_t)n * NHID);
    float*        s1    = (float*)(hbu + (size_t)n * 64);
    float*        s2    = s1 + n;
    int2*         epack = (int2*)(s2 + n);
    int*          hist  = (int*)(epack + E);
    int*          bsums = hist + n;
    int*          bsums_scan = bsums + 256;
    int*          row_ptr    = bsums_scan + 256;
    int*          cursor     = row_ptr + (n + 1);

    // Single memset covers hist + bsums (contiguous).
    hipMemsetAsync(hist, 0, ((size_t)n + 256) * sizeof(int), stream);

    gemm_h_kernel<<<(n + 127) / 128, 256, 0, stream>>>(x, W, a, h, hbu, s1, s2, n);

    hist_kernel<<<(E + 255) / 256, 256, 0, stream>>>(ei, hist, E);

    scan_block_kernel<<<nb, 256, 0, stream>>>(hist, row_ptr, bsums, n);
    scan_block_kernel<<<1, 256, 0, stream>>>(bsums, bsums_scan, nullptr, 256);
    scan_add_kernel<<<nb, 256, 0, stream>>>(row_ptr, cursor, bsums_scan, n, E);

    scatter_kernel<<<(E + 255) / 256, 256, 0, stream>>>(ei, s1, s2, cursor, epack, E);

    aggregate_kernel<<<(n + 3) / 4, 256, 0, stream>>>(row_ptr, epack, hbu, h, out, n);
}